// Round 1
// baseline (176.261 us; speedup 1.0000x reference)
//
#include <hip/hip_runtime.h>
#include <hip/hip_bf16.h>
#include <math.h>

#define VOCAB  50000
#define D_EMB  300
#define NBINS  11
#define BATCH  64
#define LQ     32
#define LD     1024
#define DTILE  64
#define NDT    (LD / DTILE)   // 16
#define BK     75             // 300 = 4 * 75

__constant__ float c_mu[NBINS]  = {1.0f, 0.9f, 0.7f, 0.5f, 0.3f, 0.1f,
                                   -0.1f, -0.3f, -0.5f, -0.7f, -0.9f};
// 1 / (2 * sigma^2):  sigma = 1e-3 -> 5e5 ; sigma = 0.1 -> 50
__constant__ float c_is2[NBINS] = {500000.0f, 50.f, 50.f, 50.f, 50.f, 50.f,
                                   50.f, 50.f, 50.f, 50.f, 50.f};

// Main kernel: one block per (batch, d-tile of 64 doc tokens).
// Computes sim = normalize(q_emb) . normalize(d_emb)^T for 32 q x 64 d,
// then RBF-bins, pools over the 64 d, writes partial pooling sums to ws.
__global__ __launch_bounds__(256) void knrm_main(
    const int* __restrict__ inputs_q, const int* __restrict__ inputs_d,
    const float* __restrict__ mask_d, const float* __restrict__ word_emb,
    float* __restrict__ partial)
{
  const int b   = blockIdx.y;
  const int dt  = blockIdx.x;
  const int tid = threadIdx.x;

  __shared__ int   qtok[LQ];
  __shared__ int   dtok[DTILE];
  __shared__ float maskd_s[DTILE];
  // k-major tiles: A2[k][q] (stride 36 -> float4 reads aligned, banks spread),
  //                B2[k][d] (stride 68 -> float2 reads aligned, banks spread)
  __shared__ __align__(16) float A2[BK][36];
  __shared__ __align__(16) float B2[BK][68];
  __shared__ float invq_s[LQ];
  __shared__ float invd_s[DTILE];
  __shared__ float red[4][LQ][NBINS];

  if (tid < LQ)  qtok[tid] = inputs_q[b * LQ + tid];
  if (tid < DTILE) {
    const int gi = b * LD + dt * DTILE + tid;
    dtok[tid]    = inputs_d[gi];
    maskd_s[tid] = mask_d[gi];
  }
  __syncthreads();

  // compute mapping: thread -> (4 q rows starting 4*tq, 2 d cols starting 2*td)
  const int tq = tid & 7;    // 0..7  -> q = 4*tq + i
  const int td = tid >> 3;   // 0..31 -> d = 2*td + j

  // staging mapping: 4 threads per row, phase = tid&3 walks cols with stride 4
  const int rowB = tid >> 2;           // 0..63 (d rows)
  const int ph   = tid & 3;
  const int rowA = (tid & 127) >> 2;   // 0..31 (q rows), threads < 128 only
  const float* embB = word_emb + (size_t)dtok[rowB] * D_EMB;
  const float* embA = word_emb + (size_t)qtok[rowA] * D_EMB;

  float acc[4][2] = {{0.f,0.f},{0.f,0.f},{0.f,0.f},{0.f,0.f}};
  float sqb = 0.f;   // sum-of-squares partial for d row (all threads)
  float sqa = 0.f;   // sum-of-squares partial for q row (threads < 128)

  for (int kb = 0; kb < D_EMB; kb += BK) {
    // ---- stage B tile (64 x 75) ----
    for (int c = ph; c < BK; c += 4) {
      const float v = embB[kb + c];
      B2[c][rowB] = v;
      sqb += v * v;
    }
    // ---- stage A tile (32 x 75) ----
    if (tid < 128) {
      for (int c = ph; c < BK; c += 4) {
        const float v = embA[kb + c];
        A2[c][rowA] = v;
        sqa += v * v;
      }
    }
    __syncthreads();

    // ---- inner product: 1 float4 + 1 float2 LDS read per k, 8 FMA ----
#pragma unroll 5
    for (int kk = 0; kk < BK; ++kk) {
      const float4 a  = *(const float4*)&A2[kk][4 * tq];
      const float2 bv = *(const float2*)&B2[kk][2 * td];
      acc[0][0] += a.x * bv.x; acc[0][1] += a.x * bv.y;
      acc[1][0] += a.y * bv.x; acc[1][1] += a.y * bv.y;
      acc[2][0] += a.z * bv.x; acc[2][1] += a.z * bv.y;
      acc[3][0] += a.w * bv.x; acc[3][1] += a.w * bv.y;
    }
    __syncthreads();
  }

  // ---- finish norms: quad-reduce the staging partials ----
  sqb += __shfl_xor(sqb, 1); sqb += __shfl_xor(sqb, 2);
  if (ph == 0) invd_s[rowB] = sqb;           // raw sumsq for now
  sqa += __shfl_xor(sqa, 1); sqa += __shfl_xor(sqa, 2);
  if (tid < 128 && ph == 0) invq_s[rowA] = sqa;
  __syncthreads();
  if (tid < DTILE) invd_s[tid] = 1.f / fmaxf(sqrtf(invd_s[tid]), 1e-12f);
  if (tid < LQ)    invq_s[tid] = 1.f / fmaxf(sqrtf(invq_s[tid]), 1e-12f);
  __syncthreads();

  // ---- RBF bins + pooling over this tile's 64 d tokens ----
  const float invd0 = invd_s[2 * td],  invd1 = invd_s[2 * td + 1];
  const float md0   = maskd_s[2 * td], md1   = maskd_s[2 * td + 1];
  float ps[4][NBINS];
#pragma unroll
  for (int i = 0; i < 4; ++i) {
    const float iq = invq_s[4 * tq + i];
    const float s0 = acc[i][0] * iq * invd0;
    const float s1 = acc[i][1] * iq * invd1;
#pragma unroll
    for (int k = 0; k < NBINS; ++k) {
      const float d0 = s0 - c_mu[k];
      const float d1 = s1 - c_mu[k];
      ps[i][k] = md0 * __expf(-d0 * d0 * c_is2[k])
               + md1 * __expf(-d1 * d1 * c_is2[k]);
    }
  }

  // reduce over the 8 td-groups within each wave (lane bits 3,4,5)
#pragma unroll
  for (int off = 8; off < 64; off <<= 1)
#pragma unroll
    for (int i = 0; i < 4; ++i)
#pragma unroll
      for (int k = 0; k < NBINS; ++k)
        ps[i][k] += __shfl_xor(ps[i][k], off);

  const int wave = tid >> 6;
  const int lane = tid & 63;
  if (lane < 8) {   // lane == tq holds sums for q = 4*lane + i
#pragma unroll
    for (int i = 0; i < 4; ++i)
#pragma unroll
      for (int k = 0; k < NBINS; ++k)
        red[wave][4 * lane + i][k] = ps[i][k];
  }
  __syncthreads();

  // combine the 4 waves, write deterministic partial to workspace
  for (int v = tid; v < LQ * NBINS; v += 256) {
    const int q = v / NBINS, k = v % NBINS;
    const float s = red[0][q][k] + red[1][q][k] + red[2][q][k] + red[3][q][k];
    partial[(((size_t)b * NDT + dt) * LQ + q) * NBINS + k] = s;
  }
}

// Finalize: reduce d-tiles, log, IDF attention weight, sum over q, dense+tanh.
__global__ __launch_bounds__(128) void knrm_finalize(
    const float* __restrict__ partial, const int* __restrict__ inputs_q,
    const float* __restrict__ mask_q, const float* __restrict__ attn_table,
    const float* __restrict__ idf_w, const float* __restrict__ idf_b,
    const float* __restrict__ dense_w, const float* __restrict__ dense_b,
    float* __restrict__ out)
{
  const int b   = blockIdx.x;
  const int tid = threadIdx.x;
  __shared__ float pool[LQ][NBINS];
  __shared__ float wq_s[LQ];
  __shared__ float lps[NBINS];

  for (int v = tid; v < LQ * NBINS; v += 128) {
    const int q = v / NBINS, k = v % NBINS;
    float s = 0.f;
    for (int t = 0; t < NDT; ++t)
      s += partial[(((size_t)b * NDT + t) * LQ + q) * NBINS + k];
    pool[q][k] = logf(fmaxf(s, 1e-10f));
  }
  if (tid < LQ) {
    const int tok = inputs_q[b * LQ + tid];
    wq_s[tid] = mask_q[b * LQ + tid] * (attn_table[tok] * idf_w[0] + idf_b[0]);
  }
  __syncthreads();
  if (tid < NBINS) {
    float s = 0.f;
    for (int q = 0; q < LQ; ++q) s += pool[q][tid] * wq_s[q];
    lps[tid] = 0.01f * s;
  }
  __syncthreads();
  if (tid == 0) {
    float z = dense_b[0];
    for (int k = 0; k < NBINS; ++k) z += lps[k] * dense_w[k];
    out[b] = tanhf(z);
  }
}

extern "C" void kernel_launch(void* const* d_in, const int* in_sizes, int n_in,
                              void* d_out, int out_size, void* d_ws, size_t ws_size,
                              hipStream_t stream) {
  const int*   inputs_q  = (const int*)d_in[0];
  const int*   inputs_d  = (const int*)d_in[1];
  const float* mask_q    = (const float*)d_in[2];
  const float* mask_d    = (const float*)d_in[3];
  const float* word_emb  = (const float*)d_in[4];
  const float* attn_tab  = (const float*)d_in[5];
  const float* idf_w     = (const float*)d_in[6];
  const float* idf_b     = (const float*)d_in[7];
  const float* dense_w   = (const float*)d_in[8];
  const float* dense_b   = (const float*)d_in[9];
  float* out     = (float*)d_out;
  float* partial = (float*)d_ws;   // B * NDT * LQ * NBINS fp32 = 1.41 MB

  dim3 grid(NDT, BATCH);
  knrm_main<<<grid, 256, 0, stream>>>(inputs_q, inputs_d, mask_d, word_emb, partial);
  knrm_finalize<<<BATCH, 128, 0, stream>>>(partial, inputs_q, mask_q, attn_tab,
                                           idf_w, idf_b, dense_w, dense_b, out);
}

// Round 2
// 135.415 us; speedup vs baseline: 1.3016x; 1.3016x over previous
//
#include <hip/hip_runtime.h>
#include <math.h>

#define VOCAB  50000
#define D_EMB  300
#define NBINS  11
#define BATCH  64
#define LQ     32
#define LD     1024
#define DTILE  64
#define NDT    (LD / DTILE)   // 16
#define NSTEP  10             // K padded to 320 = 10 * 32 (MFMA K=32 steps)

typedef __attribute__((ext_vector_type(8))) short short8;   // 8 bf16 (4 VGPRs)
typedef __attribute__((ext_vector_type(4))) float floatx4;  // MFMA C/D

__constant__ float c_mu[NBINS]  = {1.0f, 0.9f, 0.7f, 0.5f, 0.3f, 0.1f,
                                   -0.1f, -0.3f, -0.5f, -0.7f, -0.9f};
// 1 / (2*sigma^2): sigma=1e-3 -> 5e5 ; sigma=0.1 -> 50
__constant__ float c_is2[NBINS] = {500000.0f, 50.f, 50.f, 50.f, 50.f, 50.f,
                                   50.f, 50.f, 50.f, 50.f, 50.f};

static __device__ __forceinline__ unsigned short f32_bf16(float f) {
  unsigned u = __float_as_uint(f);
  u += 0x7FFFu + ((u >> 16) & 1u);          // RNE
  return (unsigned short)(u >> 16);
}
static __device__ __forceinline__ float bf16_f32(unsigned short h) {
  return __uint_as_float(((unsigned)h) << 16);
}

// Stage one 16-row region into MFMA-fragment-linear LDS layout.
// Lane l holds row (l&15), k-range 32*s + 8*(l>>4) .. +8. Writes are
// ds_write_b128 at base + l*16 -> conflict-free. Returns this lane's
// sum-of-squares partial over the bf16-ROUNDED values it staged.
static __device__ __forceinline__ float stage_rows(
    const float* __restrict__ emb_row,   // word_emb + tok*D_EMB (this lane's row)
    short* __restrict__ region,          // LDS region base (s=0 fragment block)
    int s_begin, int s_end, int khi, int lane)
{
  const float4* emb4 = (const float4*)emb_row;
  float p = 0.f;
  for (int s = s_begin; s < s_end; ++s) {
    const int k0 = 32 * s + 8 * khi;
    float4 fa = make_float4(0.f, 0.f, 0.f, 0.f);
    float4 fb = make_float4(0.f, 0.f, 0.f, 0.f);
    if (k0 < D_EMB)     fa = emb4[k0 >> 2];        // k0 multiple of 8 -> full float4 valid
    if (k0 + 4 < D_EMB) fb = emb4[(k0 >> 2) + 1];  // zero-pad K 300..319
    unsigned short h[8];
    h[0] = f32_bf16(fa.x); h[1] = f32_bf16(fa.y);
    h[2] = f32_bf16(fa.z); h[3] = f32_bf16(fa.w);
    h[4] = f32_bf16(fb.x); h[5] = f32_bf16(fb.y);
    h[6] = f32_bf16(fb.z); h[7] = f32_bf16(fb.w);
    short8 v;
#pragma unroll
    for (int j = 0; j < 8; ++j) {
      const float x = bf16_f32(h[j]);   // norm from ROUNDED values (bin-0 exactness)
      p += x * x;
      v[j] = (short)h[j];
    }
    *(short8*)(region + s * 512 + lane * 8) = v;
  }
  return p;
}

// One block = (batch b, d-tile of 64 doc tokens). bf16 MFMA for the 32x64 sim
// tile, norms folded into the epilogue, RBF + pooling, partial to workspace.
__global__ __launch_bounds__(256) void knrm_main(
    const int* __restrict__ inputs_q, const int* __restrict__ inputs_d,
    const float* __restrict__ mask_d, const float* __restrict__ word_emb,
    float* __restrict__ partial)
{
  const int b    = blockIdx.y;
  const int dt   = blockIdx.x;
  const int tid  = threadIdx.x;
  const int wid  = tid >> 6;
  const int lane = tid & 63;
  const int khi  = lane >> 4;   // 0..3
  const int rl   = lane & 15;   // 0..15

  __shared__ __align__(16) short Afrag[2 * NSTEP * 512];  // 20 KB: (qt, s) blocks
  __shared__ __align__(16) short Bfrag[4 * NSTEP * 512];  // 40 KB: (dt2, s) blocks
  __shared__ float sumsq_s[96];                           // 32 q + 64 d
  __shared__ float invq_s[LQ], invd_s[DTILE], maskd_s[DTILE];
  __shared__ float red[4][16][NBINS];

  if (tid < 96) sumsq_s[tid] = 0.f;
  if (tid < DTILE) maskd_s[tid] = mask_d[b * LD + dt * DTILE + tid];
  __syncthreads();

  // ---- staging: 60 fragment blocks split across 4 waves (15 wave-steps each)
  {
    int tok; float p;
    if (wid == 0) {
      tok = inputs_q[b * LQ + rl];                                    // A qt0, s0..9
      p = stage_rows(word_emb + (size_t)tok * D_EMB, Afrag, 0, NSTEP, khi, lane);
      p += __shfl_xor(p, 16); p += __shfl_xor(p, 32);
      if (lane < 16) atomicAdd(&sumsq_s[lane], p);
      tok = inputs_d[b * LD + dt * DTILE + rl];                       // B dt2=0, s0..4
      p = stage_rows(word_emb + (size_t)tok * D_EMB, Bfrag, 0, 5, khi, lane);
      p += __shfl_xor(p, 16); p += __shfl_xor(p, 32);
      if (lane < 16) atomicAdd(&sumsq_s[32 + lane], p);
    } else if (wid == 1) {
      tok = inputs_q[b * LQ + 16 + rl];                               // A qt1, s0..9
      p = stage_rows(word_emb + (size_t)tok * D_EMB, Afrag + NSTEP * 512, 0, NSTEP, khi, lane);
      p += __shfl_xor(p, 16); p += __shfl_xor(p, 32);
      if (lane < 16) atomicAdd(&sumsq_s[16 + lane], p);
      tok = inputs_d[b * LD + dt * DTILE + rl];                       // B dt2=0, s5..9
      p = stage_rows(word_emb + (size_t)tok * D_EMB, Bfrag, 5, NSTEP, khi, lane);
      p += __shfl_xor(p, 16); p += __shfl_xor(p, 32);
      if (lane < 16) atomicAdd(&sumsq_s[32 + lane], p);
    } else if (wid == 2) {
      tok = inputs_d[b * LD + dt * DTILE + 16 + rl];                  // B dt2=1, s0..9
      p = stage_rows(word_emb + (size_t)tok * D_EMB, Bfrag + NSTEP * 512, 0, NSTEP, khi, lane);
      p += __shfl_xor(p, 16); p += __shfl_xor(p, 32);
      if (lane < 16) atomicAdd(&sumsq_s[48 + lane], p);
      tok = inputs_d[b * LD + dt * DTILE + 32 + rl];                  // B dt2=2, s0..4
      p = stage_rows(word_emb + (size_t)tok * D_EMB, Bfrag + 2 * NSTEP * 512, 0, 5, khi, lane);
      p += __shfl_xor(p, 16); p += __shfl_xor(p, 32);
      if (lane < 16) atomicAdd(&sumsq_s[64 + lane], p);
    } else {
      tok = inputs_d[b * LD + dt * DTILE + 48 + rl];                  // B dt2=3, s0..9
      p = stage_rows(word_emb + (size_t)tok * D_EMB, Bfrag + 3 * NSTEP * 512, 0, NSTEP, khi, lane);
      p += __shfl_xor(p, 16); p += __shfl_xor(p, 32);
      if (lane < 16) atomicAdd(&sumsq_s[80 + lane], p);
      tok = inputs_d[b * LD + dt * DTILE + 32 + rl];                  // B dt2=2, s5..9
      p = stage_rows(word_emb + (size_t)tok * D_EMB, Bfrag + 2 * NSTEP * 512, 5, NSTEP, khi, lane);
      p += __shfl_xor(p, 16); p += __shfl_xor(p, 32);
      if (lane < 16) atomicAdd(&sumsq_s[64 + lane], p);
    }
  }
  __syncthreads();

  if (tid < 96) {
    const float s   = sumsq_s[tid];
    const float inv = 1.f / fmaxf(sqrtf(s), 1e-12f);
    if (tid < 32) invq_s[tid] = inv; else invd_s[tid - 32] = inv;
  }
  __syncthreads();

  // ---- MFMA: wave w computes C tiles (qt = w>>1) x (dt2 = 2*(w&1), +1)
  const int qt = wid >> 1, dp = wid & 1;
  const short* Ab = Afrag + qt * NSTEP * 512;
  const short* B0 = Bfrag + (2 * dp) * NSTEP * 512;
  const short* B1 = Bfrag + (2 * dp + 1) * NSTEP * 512;
  floatx4 acc0 = {0.f, 0.f, 0.f, 0.f};
  floatx4 acc1 = {0.f, 0.f, 0.f, 0.f};
#pragma unroll
  for (int s = 0; s < NSTEP; ++s) {
    const short8 a  = *(const short8*)(Ab + s * 512 + lane * 8);
    const short8 b0 = *(const short8*)(B0 + s * 512 + lane * 8);
    const short8 b1 = *(const short8*)(B1 + s * 512 + lane * 8);
    acc0 = __builtin_amdgcn_mfma_f32_16x16x32_bf16(a, b0, acc0, 0, 0, 0);
    acc1 = __builtin_amdgcn_mfma_f32_16x16x32_bf16(a, b1, acc1, 0, 0, 0);
  }

  // ---- epilogue: normalize, RBF bins, pool over this wave's 32 d-cols
  float ps[4][NBINS];
#pragma unroll
  for (int r = 0; r < 4; ++r)
#pragma unroll
    for (int k = 0; k < NBINS; ++k) ps[r][k] = 0.f;

  float iq[4];
#pragma unroll
  for (int r = 0; r < 4; ++r) iq[r] = invq_s[16 * qt + 4 * khi + r];

#pragma unroll
  for (int t = 0; t < 2; ++t) {
    const int   dl = 32 * dp + 16 * t + rl;   // C/D col = lane&15
    const float id = invd_s[dl];
    const float md = maskd_s[dl];
    const floatx4 acc = t ? acc1 : acc0;
#pragma unroll
    for (int r = 0; r < 4; ++r) {             // C/D row = 4*(lane>>4)+r
      const float sv = acc[r] * iq[r] * id;
#pragma unroll
      for (int k = 0; k < NBINS; ++k) {
        const float d = sv - c_mu[k];
        ps[r][k] += md * __expf(-d * d * c_is2[k]);
      }
    }
  }

#pragma unroll
  for (int off = 1; off < 16; off <<= 1)
#pragma unroll
    for (int r = 0; r < 4; ++r)
#pragma unroll
      for (int k = 0; k < NBINS; ++k)
        ps[r][k] += __shfl_xor(ps[r][k], off);

  if (rl == 0)
#pragma unroll
    for (int r = 0; r < 4; ++r)
#pragma unroll
      for (int k = 0; k < NBINS; ++k)
        red[wid][4 * khi + r][k] = ps[r][k];
  __syncthreads();

  // partial layout: [b][q][k][dt] so finalize reads 16 contiguous floats
  for (int v = tid; v < LQ * NBINS; v += 256) {
    const int q = v / NBINS, k = v % NBINS;
    const float sv = (q < 16) ? (red[0][q][k] + red[1][q][k])
                              : (red[2][q - 16][k] + red[3][q - 16][k]);
    partial[((size_t)(b * LQ + q) * NBINS + k) * NDT + dt] = sv;
  }
}

// Finalize: reduce d-tiles, log, IDF attention weight, sum over q, dense+tanh.
__global__ __launch_bounds__(128) void knrm_finalize(
    const float* __restrict__ partial, const int* __restrict__ inputs_q,
    const float* __restrict__ mask_q, const float* __restrict__ attn_table,
    const float* __restrict__ idf_w, const float* __restrict__ idf_b,
    const float* __restrict__ dense_w, const float* __restrict__ dense_b,
    float* __restrict__ out)
{
  const int b   = blockIdx.x;
  const int tid = threadIdx.x;
  __shared__ float pool[LQ][NBINS];
  __shared__ float wq_s[LQ];
  __shared__ float lps[NBINS];

  for (int v = tid; v < LQ * NBINS; v += 128) {
    const int q = v / NBINS, k = v % NBINS;
    const float* p = partial + ((size_t)(b * LQ + q) * NBINS + k) * NDT;
    float s = 0.f;
#pragma unroll
    for (int t = 0; t < NDT; ++t) s += p[t];
    pool[q][k] = logf(fmaxf(s, 1e-10f));
  }
  if (tid < LQ) {
    const int tok = inputs_q[b * LQ + tid];
    wq_s[tid] = mask_q[b * LQ + tid] * (attn_table[tok] * idf_w[0] + idf_b[0]);
  }
  __syncthreads();
  if (tid < NBINS) {
    float s = 0.f;
    for (int q = 0; q < LQ; ++q) s += pool[q][tid] * wq_s[q];
    lps[tid] = 0.01f * s;
  }
  __syncthreads();
  if (tid == 0) {
    float z = dense_b[0];
    for (int k = 0; k < NBINS; ++k) z += lps[k] * dense_w[k];
    out[b] = tanhf(z);
  }
}

extern "C" void kernel_launch(void* const* d_in, const int* in_sizes, int n_in,
                              void* d_out, int out_size, void* d_ws, size_t ws_size,
                              hipStream_t stream) {
  const int*   inputs_q  = (const int*)d_in[0];
  const int*   inputs_d  = (const int*)d_in[1];
  const float* mask_q    = (const float*)d_in[2];
  const float* mask_d    = (const float*)d_in[3];
  const float* word_emb  = (const float*)d_in[4];
  const float* attn_tab  = (const float*)d_in[5];
  const float* idf_w     = (const float*)d_in[6];
  const float* idf_b     = (const float*)d_in[7];
  const float* dense_w   = (const float*)d_in[8];
  const float* dense_b   = (const float*)d_in[9];
  float* out     = (float*)d_out;
  float* partial = (float*)d_ws;   // B*LQ*NBINS*NDT fp32 = 1.41 MB

  dim3 grid(NDT, BATCH);
  knrm_main<<<grid, 256, 0, stream>>>(inputs_q, inputs_d, mask_d, word_emb, partial);
  knrm_finalize<<<BATCH, 128, 0, stream>>>(partial, inputs_q, mask_q, attn_tab,
                                           idf_w, idf_b, dense_w, dense_b, out);
}